// Round 4
// baseline (418.682 us; speedup 1.0000x reference)
//
#include <hip/hip_runtime.h>
#include <hip/hip_bf16.h>
#include <stdint.h>

#define NUM_EMB 4096
#define EMB_DIM 256
#define NVEC 65536                     // 64*32*32
#define OUT0_SIZE (NVEC * EMB_DIM)     // z_q_ste elements; loss scalar follows
#define MTILE 128                      // z rows per block
#define NTILE 64                       // codebook entries per LDS tile
#define DCONST 0.0625f                 // positivity shift for packed distance

typedef __bf16 bf16x8 __attribute__((ext_vector_type(8)));
typedef float floatx16 __attribute__((ext_vector_type(16)));

static __device__ __forceinline__ unsigned int f2bf(float f) {
  unsigned int u = __float_as_uint(f);
  return (u + 0x7fffu + ((u >> 16) & 1u)) >> 16;  // RNE fp32->bf16
}

static __device__ __forceinline__ uint4 pack_bf8(float4 a, float4 b) {
  uint4 r;
  r.x = f2bf(a.x) | (f2bf(a.y) << 16);
  r.y = f2bf(a.z) | (f2bf(a.w) << 16);
  r.z = f2bf(b.x) | (f2bf(b.y) << 16);
  r.w = f2bf(b.z) | (f2bf(b.w) << 16);
  return r;
}

// Prep: codebook fp32 -> bf16 (ws), ||e||^2 + DCONST (ws), zero loss slot.
__global__ void __launch_bounds__(256) vq_prep(const float* __restrict__ cbf,
                                               unsigned short* __restrict__ cbb,
                                               float* __restrict__ enorm,
                                               float* __restrict__ out) {
  int w = threadIdx.x >> 6;
  int lane = threadIdx.x & 63;
  int row = blockIdx.x * 4 + w;
  float4 v = ((const float4*)(cbf + (size_t)row * EMB_DIM))[lane];
  float ss = v.x * v.x + v.y * v.y + v.z * v.z + v.w * v.w;
  ushort4 b;
  b.x = (unsigned short)f2bf(v.x);
  b.y = (unsigned short)f2bf(v.y);
  b.z = (unsigned short)f2bf(v.z);
  b.w = (unsigned short)f2bf(v.w);
  ((ushort4*)(cbb + (size_t)row * EMB_DIM))[lane] = b;
#pragma unroll
  for (int m = 1; m < 64; m <<= 1) ss += __shfl_xor(ss, m, 64);
  if (lane == 0) enorm[row] = ss + DCONST;
  if (blockIdx.x == 0 && threadIdx.x == 0) out[OUT0_SIZE] = 0.0f;
}

// Zero a floatx16 accumulator.
#define ZERO16(ACC)                                   \
  {                                                   \
    _Pragma("unroll") for (int r_ = 0; r_ < 16; ++r_) \
        (ACC)[r_] = 0.f;                              \
  }

// One 16-MFMA chain for ACC (row-group AG) from LDS base BP; when DOEPI,
// interleave the packed-argmin epilogue of PACC (pmin offset POFF) using
// ENP/COLBP. sched_group_barrier pins {1 ds_read, 1 mfma, 3 valu} per step
// so the epilogue VALU executes in the MFMA pipe shadow.
#define CHAIN(BP, ACC, AG, PACC, POFF, DOEPI, ENP, COLBP)                     \
  {                                                                           \
    _Pragma("unroll") for (int ks_ = 0; ks_ < 16; ++ks_) {                    \
      uint4 bv_ = *(const uint4*)((BP) + ((ks_ * 32 + h * 16) ^ sx4));        \
      bf16x8 bb_ = __builtin_bit_cast(bf16x8, bv_);                           \
      ACC = __builtin_amdgcn_mfma_f32_32x32x16_bf16(                          \
          __builtin_bit_cast(bf16x8, afrag[AG][ks_]), bb_, ACC, 0, 0, 0);     \
      if (DOEPI) {                                                            \
        float d_ = fmaf(-2.f, (PACC)[ks_], (ENP));                            \
        unsigned int q_ = (__float_as_uint(d_) & 0xFFFFF000u) | (COLBP);      \
        pmin[(POFF) + ks_] = min(pmin[(POFF) + ks_], q_);                     \
        __builtin_amdgcn_sched_group_barrier(0x100, 1, 0);                    \
        __builtin_amdgcn_sched_group_barrier(0x008, 1, 0);                    \
        __builtin_amdgcn_sched_group_barrier(0x002, 3, 0);                    \
      }                                                                       \
    }                                                                         \
  }

// Main: distance-GEMM, async DMA double-buffer (1 barrier/tile), split-chain
// software pipeline: epi(acc1[t-1]) under acc0[t]'s MFMAs, epi(acc0[t]) under
// acc1[t]'s MFMAs — VALU argmin hides in the MFMA pipe shadow, no extra accs.
__global__ void __launch_bounds__(256, 2) vq_main(const float* __restrict__ z,
                                                  const float* __restrict__ cbf,
                                                  const unsigned short* __restrict__ cbb,
                                                  const float* __restrict__ enorm,
                                                  float* __restrict__ out) {
  __shared__ __align__(16) unsigned char sstage[2][NTILE * 512];  // 64 KB dbuf
  __shared__ unsigned int minlds[2][MTILE];
  __shared__ int idx_lds[MTILE];
  __shared__ float wsum[4];
  __shared__ float zwsum[2];

  const int t = threadIdx.x;
  const int w = t >> 6;
  const int lane = t & 63;
  const int h = lane >> 5;     // half-wave
  const int eL = lane & 31;
  const int rg = w & 1;        // row group: rows rg*64..+63 of the block tile
  const int cg = w >> 1;       // col group: cols cg*32..+31 of each 64-entry tile
  const int blk = blockIdx.x;
  const int row_base = blk * MTILE + rg * 64;

  // Async DMA of one 64x256 bf16 codebook tile into sstage[buf].
  // LDS dest is linear (wave-uniform base + lane*16); bank swizzle applied by
  // permuting the GLOBAL source 16B-slot: s ^= (entry & 7).
  auto stage_tile = [&](int buf, int c0) {
#pragma unroll
    for (int j = 0; j < 8; ++j) {
      int e = (w << 4) + (j << 1) + h;          // entry within tile
      int s = eL ^ (e & 7);                     // swizzled source slot
      const unsigned short* src = cbb + ((size_t)(c0 + e) << 8) + (s << 3);
      __builtin_amdgcn_global_load_lds(
          (const __attribute__((address_space(1))) void*)src,
          (__attribute__((address_space(3))) void*)&sstage[buf][(w << 13) + (j << 10)],
          16, 0, 0);
    }
  };

  // Kick off tile 0 DMA before the A-phase so its latency hides under z loads.
  stage_tile(0, 0);
  const int laneoff = cg * 32 + eL;

  // ---- A-phase: 64 z rows (2 groups of 32) x D=256 as bf16 into registers.
  // A layout for 32x32x16: m = lane&31, k = (lane>>5)*8 + j, per 16-k step.
  uint4 afrag[2][16];
  float zn[2] = {0.f, 0.f};
#pragma unroll
  for (int g = 0; g < 2; ++g) {
    const float* rp = z + (size_t)(row_base + g * 32 + eL) * EMB_DIM + h * 8;
#pragma unroll
    for (int ks = 0; ks < 16; ++ks) {
      float4 a0 = *(const float4*)(rp + ks * 16);
      float4 a1 = *(const float4*)(rp + ks * 16 + 4);
      zn[g] += a0.x * a0.x + a0.y * a0.y + a0.z * a0.z + a0.w * a0.w
             + a1.x * a1.x + a1.y * a1.y + a1.z * a1.z + a1.w * a1.w;
      afrag[g][ks] = pack_bf8(a0, a1);
    }
    zn[g] += __shfl_xor(zn[g], 32, 64);
  }
  // Sum ||z||^2 over this wave's 64 rows (waves with cg==0 cover all 128 rows).
  if (cg == 0) {
    float zs = zn[0] + zn[1];
#pragma unroll
    for (int m = 1; m <= 16; m <<= 1) zs += __shfl_xor(zs, m, 64);
    if (lane == 0) zwsum[rg] = zs;
  }

  // Running packed argmin: top-20 bits of positive distance | 12-bit col.
  unsigned int pmin[32];
#pragma unroll
  for (int s = 0; s < 32; ++s) pmin[s] = 0xFFFFFFFFu;

  floatx16 acc0, acc1;

  __syncthreads();  // drains vmcnt: tile-0 DMA + A loads complete

  const int sx4 = (eL & 7) << 4;  // read-side slot swizzle (matches stage)
  const unsigned char* bpE = &sstage[0][(size_t)laneoff * 512];
  const unsigned char* bpO = &sstage[1][(size_t)laneoff * 512];

  float enC = enorm[laneoff];                 // en of tile being computed
  float enP = 0.f;                            // en of previous tile (acc1 epi)
  unsigned int colbC = (unsigned int)laneoff;
  unsigned int colbP = 0u;
  float enN;

  for (int c0 = 0; c0 < NUM_EMB; c0 += 2 * NTILE) {
    // ===== even tile (buf0) =====
    stage_tile(1, c0 + NTILE);
    enN = enorm[c0 + NTILE + laneoff];
    ZERO16(acc0);
    if (c0 == 0) {
      CHAIN(bpE, acc0, 0, acc1, 16, 0, 0.f, 0u);        // no prev epi
    } else {
      CHAIN(bpE, acc0, 0, acc1, 16, 1, enP, colbP);     // epi acc1(t-1)
    }
    asm volatile("" ::: "memory");  // keep phases' LDS reads from CSE-merging
    ZERO16(acc1);
    CHAIN(bpE, acc1, 1, acc0, 0, 1, enC, colbC);        // epi acc0(even tile)
    enP = enC; colbP = colbC;
    enC = enN; colbC = (unsigned int)(c0 + NTILE + laneoff);
    __syncthreads();  // buf1 DMA landed; buf0 reads done

    // ===== odd tile (buf1) =====
    int c2 = c0 + 2 * NTILE;
    if (c2 < NUM_EMB) {
      stage_tile(0, c2);
      enN = enorm[c2 + laneoff];
    }
    ZERO16(acc0);
    CHAIN(bpO, acc0, 0, acc1, 16, 1, enP, colbP);       // epi acc1(even tile)
    asm volatile("" ::: "memory");
    ZERO16(acc1);
    CHAIN(bpO, acc1, 1, acc0, 0, 1, enC, colbC);        // epi acc0(odd tile)
    enP = enC; colbP = colbC;
    if (c2 < NUM_EMB) {
      enC = enN;
      colbC = (unsigned int)(c2 + laneoff);
    }
    __syncthreads();  // buf0 DMA landed; buf1 reads done
  }
  // Final epilogue: acc1 of the last tile (state in enP/colbP).
#pragma unroll
  for (int r = 0; r < 16; ++r) {
    float d = fmaf(-2.f, acc1[r], enP);
    unsigned int q = (__float_as_uint(d) & 0xFFFFF000u) | colbP;
    pmin[16 + r] = min(pmin[16 + r], q);
  }

  // Reduce over the 32 col-lanes (xor 1..16 stays within half-wave; halves
  // cover disjoint row sets). Packed u32 min = (distance, index) lexicographic
  // -> smallest-index tiebreak like np.argmin.
#pragma unroll
  for (int s = 0; s < 32; ++s) {
    unsigned int v = pmin[s];
#pragma unroll
    for (int m = 1; m <= 16; m <<= 1) {
      unsigned int o = __shfl_xor(v, m, 64);
      if (o < v) v = o;
    }
    pmin[s] = v;
  }
  // C/D layout 32x32: row = (reg&3) + 8*(reg>>2) + 4*(lane>>5), col = lane&31.
  if (eL == 0) {
#pragma unroll
    for (int s = 0; s < 32; ++s) {
      int g = s >> 4, reg = s & 15;
      int rowl = rg * 64 + g * 32 + (reg & 3) + 8 * (reg >> 2) + 4 * h;
      minlds[cg][rowl] = pmin[s];
    }
  }
  __syncthreads();

  // Combine col-halves; recover idx + distance; loss = sum(||z||^2 + d - C).
  float rl = 0.f;
  if (t < MTILE) {
    unsigned int m0 = minlds[0][t], m1 = minlds[1][t];
    unsigned int m = m1 < m0 ? m1 : m0;
    idx_lds[t] = (int)(m & 0xFFFu);
    rl = __uint_as_float(m & 0xFFFFF000u) - DCONST;
  }
#pragma unroll
  for (int m = 1; m < 64; m <<= 1) rl += __shfl_xor(rl, m, 64);
  if (lane == 0) wsum[w] = rl;
  __syncthreads();
  if (t == 0) {
    float s = (wsum[0] + wsum[1]) + (wsum[2] + wsum[3]) + zwsum[0] + zwsum[1];
    atomicAdd(out + OUT0_SIZE, s * (1.25f / (float)OUT0_SIZE));
  }

  // Gather phase: out = codebook[idx] (== z + (z_q - z) to ~3e-7).
#pragma unroll 4
  for (int j = 0; j < 32; ++j) {
    int id4 = j * 256 + t;     // float4 index within 128x256 tile
    int r = id4 >> 6, c4 = id4 & 63;
    int k = idx_lds[r];
    float4 ev = ((const float4*)(cbf + (size_t)k * EMB_DIM))[c4];
    ((float4*)(out + (size_t)(blk * MTILE + r) * EMB_DIM))[c4] = ev;
  }
}

extern "C" void kernel_launch(void* const* d_in, const int* in_sizes, int n_in,
                              void* d_out, int out_size, void* d_ws, size_t ws_size,
                              hipStream_t stream) {
  const float* z = (const float*)d_in[0];
  const float* cbf = (const float*)d_in[1];
  unsigned short* cbb = (unsigned short*)d_ws;                           // 2 MB bf16 codebook
  float* enorm = (float*)((char*)d_ws + (size_t)NUM_EMB * EMB_DIM * 2);  // +16 KB
  float* out = (float*)d_out;
  vq_prep<<<NUM_EMB / 4, 256, 0, stream>>>(cbf, cbb, enorm, out);
  vq_main<<<NVEC / MTILE, 256, 0, stream>>>(z, cbf, cbb, enorm, out);
}

// Round 5
// 299.421 us; speedup vs baseline: 1.3983x; 1.3983x over previous
//
#include <hip/hip_runtime.h>
#include <hip/hip_bf16.h>
#include <stdint.h>

#define NUM_EMB 4096
#define EMB_DIM 256
#define NVEC 65536                     // 64*32*32
#define OUT0_SIZE (NVEC * EMB_DIM)     // z_q_ste elements; loss scalar follows
#define MTILE 128                      // z rows per block
#define NTILE 64                       // codebook entries per LDS tile
#define DCONST 0.0625f                 // positivity shift for packed distance

typedef __bf16 bf16x8 __attribute__((ext_vector_type(8)));
typedef float floatx16 __attribute__((ext_vector_type(16)));

static __device__ __forceinline__ unsigned int f2bf(float f) {
  unsigned int u = __float_as_uint(f);
  return (u + 0x7fffu + ((u >> 16) & 1u)) >> 16;  // RNE fp32->bf16
}

static __device__ __forceinline__ uint4 pack_bf8(float4 a, float4 b) {
  uint4 r;
  r.x = f2bf(a.x) | (f2bf(a.y) << 16);
  r.y = f2bf(a.z) | (f2bf(a.w) << 16);
  r.z = f2bf(b.x) | (f2bf(b.y) << 16);
  r.w = f2bf(b.z) | (f2bf(b.w) << 16);
  return r;
}

// Prep: codebook fp32 -> bf16 (ws), ||e||^2 + DCONST (ws), zero loss slot.
__global__ void __launch_bounds__(256) vq_prep(const float* __restrict__ cbf,
                                               unsigned short* __restrict__ cbb,
                                               float* __restrict__ enorm,
                                               float* __restrict__ out) {
  int w = threadIdx.x >> 6;
  int lane = threadIdx.x & 63;
  int row = blockIdx.x * 4 + w;
  float4 v = ((const float4*)(cbf + (size_t)row * EMB_DIM))[lane];
  float ss = v.x * v.x + v.y * v.y + v.z * v.z + v.w * v.w;
  ushort4 b;
  b.x = (unsigned short)f2bf(v.x);
  b.y = (unsigned short)f2bf(v.y);
  b.z = (unsigned short)f2bf(v.z);
  b.w = (unsigned short)f2bf(v.w);
  ((ushort4*)(cbb + (size_t)row * EMB_DIM))[lane] = b;
#pragma unroll
  for (int m = 1; m < 64; m <<= 1) ss += __shfl_xor(ss, m, 64);
  if (lane == 0) enorm[row] = ss + DCONST;
  if (blockIdx.x == 0 && threadIdx.x == 0) out[OUT0_SIZE] = 0.0f;
}

// Main: distance-GEMM, round-2 pipeline (async DMA double-buffer, 1 barrier
// per 64-entry tile) at doubled occupancy: 512-thread blocks, 8 waves of
// 32 rows x 32 cols -> 4 waves/SIMD (vs 2), half the per-wave registers.
// TLP (not hand-scheduling) hides ds_read latency, epilogue VALU, barriers.
__global__ void __launch_bounds__(512, 4) vq_main(const float* __restrict__ z,
                                                  const float* __restrict__ cbf,
                                                  const unsigned short* __restrict__ cbb,
                                                  const float* __restrict__ enorm,
                                                  float* __restrict__ out) {
  __shared__ __align__(16) unsigned char sstage[2][NTILE * 512];  // 64 KB dbuf
  __shared__ unsigned int minlds[2][MTILE];
  __shared__ int idx_lds[MTILE];
  __shared__ float wsum[8];
  __shared__ float zwsum[4];

  const int t = threadIdx.x;
  const int w = t >> 6;        // 8 waves
  const int lane = t & 63;
  const int h = lane >> 5;     // half-wave
  const int eL = lane & 31;
  const int rg = w >> 1;       // row group: rows rg*32..+31 of the block tile
  const int cg = w & 1;        // col group: cols cg*32..+31 of each 64-entry tile
  const int blk = blockIdx.x;
  const int row_base = blk * MTILE + rg * 32;

  // Async DMA of one 64x256 bf16 codebook tile into sstage[buf].
  // LDS dest is linear (wave-uniform base + lane*16); bank swizzle applied by
  // permuting the GLOBAL source 16B-slot: s ^= (entry & 7). 4 instr/wave.
  auto stage_tile = [&](int buf, int c0) {
#pragma unroll
    for (int j = 0; j < 4; ++j) {
      int e = (w << 3) + (j << 1) + h;          // entry within tile
      int s = eL ^ (e & 7);                     // swizzled source slot
      const unsigned short* src = cbb + ((size_t)(c0 + e) << 8) + (s << 3);
      __builtin_amdgcn_global_load_lds(
          (const __attribute__((address_space(1))) void*)src,
          (__attribute__((address_space(3))) void*)&sstage[buf][(w << 12) + (j << 10)],
          16, 0, 0);
    }
  };

  // Kick off tile 0 DMA before the A-phase so its latency hides under z loads.
  stage_tile(0, 0);
  const int laneoff = cg * 32 + eL;

  // ---- A-phase: 32 z rows x D=256 as bf16 into registers.
  // A layout for 32x32x16: m = lane&31, k = (lane>>5)*8 + j, per 16-k step.
  uint4 afrag[16];
  float zn = 0.f;
  {
    const float* rp = z + (size_t)(row_base + eL) * EMB_DIM + h * 8;
#pragma unroll
    for (int ks = 0; ks < 16; ++ks) {
      float4 a0 = *(const float4*)(rp + ks * 16);
      float4 a1 = *(const float4*)(rp + ks * 16 + 4);
      zn += a0.x * a0.x + a0.y * a0.y + a0.z * a0.z + a0.w * a0.w
          + a1.x * a1.x + a1.y * a1.y + a1.z * a1.z + a1.w * a1.w;
      afrag[ks] = pack_bf8(a0, a1);
    }
    zn += __shfl_xor(zn, 32, 64);  // both col-halves of the row
  }
  // Sum ||z||^2 over this wave's 32 rows (cg==0 waves cover all 128 rows).
  if (cg == 0) {
    float zs = zn;
#pragma unroll
    for (int m = 1; m <= 16; m <<= 1) zs += __shfl_xor(zs, m, 64);
    if (lane == 0) zwsum[rg] = zs;
  }

  // Running packed argmin: top-20 bits of positive distance | 12-bit col.
  unsigned int pmin[16];
#pragma unroll
  for (int s = 0; s < 16; ++s) pmin[s] = 0xFFFFFFFFu;

  __syncthreads();  // drains vmcnt: tile-0 DMA + A loads complete

  const int sx4 = (eL & 7) << 4;  // read-side slot swizzle (matches stage)
  int cur = 0;
  float enC = enorm[laneoff];
  for (int c0 = 0; c0 < NUM_EMB; c0 += NTILE) {
    // Prefetch tile t+1 into the other buffer; lands during this compute.
    int c1 = c0 + NTILE;
    float enN = enC;
    if (c1 < NUM_EMB) {
      stage_tile(cur ^ 1, c1);
      enN = enorm[c1 + laneoff];
    }

    // Wave computes its 32x32 sub-tile: 16 k-steps.
    floatx16 acc;
#pragma unroll
    for (int r = 0; r < 16; ++r) acc[r] = 0.f;
    const unsigned char* bp = &sstage[cur][(size_t)laneoff * 512];
#pragma unroll
    for (int ks = 0; ks < 16; ++ks) {
      uint4 bv = *(const uint4*)(bp + ((ks * 32 + h * 16) ^ sx4));
      bf16x8 b = __builtin_bit_cast(bf16x8, bv);
      acc = __builtin_amdgcn_mfma_f32_32x32x16_bf16(
          __builtin_bit_cast(bf16x8, afrag[ks]), b, acc, 0, 0, 0);
    }

    // d = -2*(z.e) + (||e||^2 + C) > 0; pack top-20 bits with col index.
    unsigned int colb = (unsigned int)(c0 + laneoff);
#pragma unroll
    for (int reg = 0; reg < 16; ++reg) {
      float d = fmaf(-2.f, acc[reg], enC);
      unsigned int p = (__float_as_uint(d) & 0xFFFFF000u) | colb;
      pmin[reg] = min(pmin[reg], p);
    }

    __syncthreads();  // single barrier/tile: drains next-tile DMA (vmcnt(0))
    cur ^= 1;
    enC = enN;
  }

  // Reduce over the 32 col-lanes (xor 1..16 stays within half-wave; halves
  // cover disjoint row sets). Packed u32 min = (distance, index) lexicographic
  // -> smallest-index tiebreak like np.argmin.
#pragma unroll
  for (int s = 0; s < 16; ++s) {
    unsigned int v = pmin[s];
#pragma unroll
    for (int m = 1; m <= 16; m <<= 1) {
      unsigned int o = __shfl_xor(v, m, 64);
      if (o < v) v = o;
    }
    pmin[s] = v;
  }
  // C/D layout 32x32: row = (reg&3) + 8*(reg>>2) + 4*(lane>>5), col = lane&31.
  if (eL == 0) {
#pragma unroll
    for (int s = 0; s < 16; ++s) {
      int rowl = rg * 32 + (s & 3) + 8 * (s >> 2) + 4 * h;
      minlds[cg][rowl] = pmin[s];
    }
  }
  __syncthreads();

  // Combine col-halves; recover idx + distance; loss = sum(||z||^2 + d - C).
  float rl = 0.f;
  if (t < MTILE) {
    unsigned int m0 = minlds[0][t], m1 = minlds[1][t];
    unsigned int m = m1 < m0 ? m1 : m0;
    idx_lds[t] = (int)(m & 0xFFFu);
    rl = __uint_as_float(m & 0xFFFFF000u) - DCONST;
  }
#pragma unroll
  for (int m = 1; m < 64; m <<= 1) rl += __shfl_xor(rl, m, 64);
  if (lane == 0) wsum[w] = rl;
  __syncthreads();
  if (t == 0) {
    float s = ((wsum[0] + wsum[1]) + (wsum[2] + wsum[3]))
            + ((wsum[4] + wsum[5]) + (wsum[6] + wsum[7]))
            + (zwsum[0] + zwsum[1]) + (zwsum[2] + zwsum[3]);
    atomicAdd(out + OUT0_SIZE, s * (1.25f / (float)OUT0_SIZE));
  }

  // Gather phase: out = codebook[idx] (== z + (z_q - z) to ~3e-7).
#pragma unroll 4
  for (int j = 0; j < 16; ++j) {
    int id4 = j * 512 + t;     // float4 index within 128x256 tile
    int r = id4 >> 6, c4 = id4 & 63;
    int k = idx_lds[r];
    float4 ev = ((const float4*)(cbf + (size_t)k * EMB_DIM))[c4];
    ((float4*)(out + (size_t)(blk * MTILE + r) * EMB_DIM))[c4] = ev;
  }
}

extern "C" void kernel_launch(void* const* d_in, const int* in_sizes, int n_in,
                              void* d_out, int out_size, void* d_ws, size_t ws_size,
                              hipStream_t stream) {
  const float* z = (const float*)d_in[0];
  const float* cbf = (const float*)d_in[1];
  unsigned short* cbb = (unsigned short*)d_ws;                           // 2 MB bf16 codebook
  float* enorm = (float*)((char*)d_ws + (size_t)NUM_EMB * EMB_DIM * 2);  // +16 KB
  float* out = (float*)d_out;
  vq_prep<<<NUM_EMB / 4, 256, 0, stream>>>(cbf, cbb, enorm, out);
  vq_main<<<NVEC / MTILE, 512, 0, stream>>>(z, cbf, cbb, enorm, out);
}